// Round 1
// 259.087 us; speedup vs baseline: 1.4848x; 1.4848x over previous
//
#include <hip/hip_runtime.h>

typedef unsigned short u16;
typedef unsigned int u32;
typedef short bf16x8 __attribute__((ext_vector_type(8)));
typedef short bf16x4 __attribute__((ext_vector_type(4)));
typedef float f32x4 __attribute__((ext_vector_type(4)));

#define LOG2E 1.4426950408889634f

__device__ __forceinline__ u16 f2b(float f) {
  u32 u = __builtin_bit_cast(u32, f);
  u32 r = (u + 0x7FFFu + ((u >> 16) & 1u)) >> 16;
  return (u16)r;
}
__device__ __forceinline__ float b2f(u16 h) {
  u32 u = ((u32)h) << 16;
  return __builtin_bit_cast(float, u);
}

// 8 consecutive elements as bf16x8; F32 selects fp32-source (convert) vs bf16.
template <bool F32>
__device__ __forceinline__ bf16x8 load8(const void* base, size_t idx) {
  if (F32) {
    const float* p = (const float*)base + idx;
    const f32x4 a = *(const f32x4*)p;
    const f32x4 b = *(const f32x4*)(p + 4);
    bf16x8 r = { (short)f2b(a[0]), (short)f2b(a[1]), (short)f2b(a[2]),
                 (short)f2b(a[3]), (short)f2b(b[0]), (short)f2b(b[1]),
                 (short)f2b(b[2]), (short)f2b(b[3]) };
    return r;
  }
  return *(const bf16x8*)((const u16*)base + idx);
}

// async global->LDS, 16B per lane; lds dest must be wave-uniform base.
__device__ __forceinline__ void gl_lds16(const u16* g, u16* l) {
  __builtin_amdgcn_global_load_lds(
      (const __attribute__((address_space(1))) u32*)(const void*)g,
      (__attribute__((address_space(3))) u32*)(void*)l, 16, 0, 0);
}

// ---------------------------------------------------------------------------
// NT GEMM core (R9-verified): C[128x128] += A * W^T, K=1024.
// ---------------------------------------------------------------------------
template <bool AF32>
__device__ __forceinline__ void gemm_core(const void* A, const float* W,
                                          int m0, int n0, int tid,
                                          u16* As, u16* Bs,
                                          f32x4 (&acc)[4][4]) {
  const int lane = tid & 63, wave = tid >> 6;
  const int wr = wave >> 1, wc = wave & 1;
  const int l15 = lane & 15, quad = lane >> 4;
  const int r0 = tid >> 2;
  const int c8 = (tid & 3) << 3;

  const size_t ia0 = (size_t)(m0 + r0) * 1024 + c8;
  const size_t ia1 = ia0 + (size_t)64 * 1024;
  const size_t iw0 = (size_t)(n0 + r0) * 1024 + c8;
  const size_t iw1 = iw0 + (size_t)64 * 1024;

  u16* sa0 = As + r0 * 40 + c8;
  u16* sa1 = sa0 + 64 * 40;
  u16* sb0 = Bs + r0 * 40 + c8;
  u16* sb1 = sb0 + 64 * 40;

  const u16* ar = As + (wr * 64 + l15) * 40 + quad * 8;
  const u16* br = Bs + (wc * 64 + l15) * 40 + quad * 8;

  bf16x8 ra0 = load8<AF32>(A, ia0);
  bf16x8 ra1 = load8<AF32>(A, ia1);
  bf16x8 rw0 = load8<true>(W, iw0);
  bf16x8 rw1 = load8<true>(W, iw1);

  for (int k0 = 0; k0 < 1024; k0 += 32) {
    *(bf16x8*)sa0 = ra0;
    *(bf16x8*)sa1 = ra1;
    *(bf16x8*)sb0 = rw0;
    *(bf16x8*)sb1 = rw1;
    __syncthreads();
    if (k0 + 32 < 1024) {
      ra0 = load8<AF32>(A, ia0 + k0 + 32);
      ra1 = load8<AF32>(A, ia1 + k0 + 32);
      rw0 = load8<true>(W, iw0 + k0 + 32);
      rw1 = load8<true>(W, iw1 + k0 + 32);
    }
    bf16x8 af[4], bfr[4];
#pragma unroll
    for (int i = 0; i < 4; ++i) af[i] = *(const bf16x8*)(ar + i * 16 * 40);
#pragma unroll
    for (int i = 0; i < 4; ++i) bfr[i] = *(const bf16x8*)(br + i * 16 * 40);
#pragma unroll
    for (int mt = 0; mt < 4; ++mt)
#pragma unroll
      for (int nt = 0; nt < 4; ++nt)
        acc[mt][nt] = __builtin_amdgcn_mfma_f32_16x16x32_bf16(
            af[mt], bfr[nt], acc[mt][nt], 0, 0, 0);
    __syncthreads();
  }
}

// ---------------------------------------------------------------------------
// Fused QKV projection. x, W fp32 in; q/k bf16 token-major; V transposed:
// vt[(b*1024+e)*2048 + s]. blockIdx.y: [0..7]=Q, [8..15]=K, [16..23]=V.
// ---------------------------------------------------------------------------
__global__ __launch_bounds__(256, 2) void gemm_qkv_kernel(
    const float* __restrict__ x, const float* __restrict__ wq,
    const float* __restrict__ wk, const float* __restrict__ wv,
    u16* __restrict__ qo, u16* __restrict__ ko, u16* __restrict__ vt) {
  __shared__ __align__(16) u16 As[128 * 40];
  __shared__ __align__(16) u16 Bs[128 * 40];
  const int tid = threadIdx.x;
  const int m0 = blockIdx.x * 128;
  const int mat = blockIdx.y >> 3;
  const int n0 = (blockIdx.y & 7) * 128;
  const float* W = (mat == 0) ? wq : ((mat == 1) ? wk : wv);

  f32x4 acc[4][4] = {};
  gemm_core<true>(x, W, m0, n0, tid, As, Bs, acc);

  const int lane = tid & 63, wave = tid >> 6;
  const int wr = wave >> 1, wc = wave & 1;
  const int l15 = lane & 15, quad = lane >> 4;

  if (mat < 2) {
    u16* out = (mat == 0) ? qo : ko;
#pragma unroll
    for (int mt = 0; mt < 4; ++mt) {
      const int gr = m0 + wr * 64 + mt * 16 + quad * 4;
#pragma unroll
      for (int nt = 0; nt < 4; ++nt) {
        const int gc = n0 + wc * 64 + nt * 16 + l15;
#pragma unroll
        for (int r = 0; r < 4; ++r)
          out[(size_t)(gr + r) * 1024 + gc] = f2b(acc[mt][nt][r]);
      }
    }
  } else {
    // vt[(b*1024 + e)*2048 + s]; 4 consecutive s per lane -> 8B store
#pragma unroll
    for (int mt = 0; mt < 4; ++mt) {
      const int gr = m0 + wr * 64 + mt * 16 + quad * 4;  // token idx b*2048+s
      const int b = gr >> 11;
      const int s = gr & 2047;
#pragma unroll
      for (int nt = 0; nt < 4; ++nt) {
        const int gc = n0 + wc * 64 + nt * 16 + l15;     // embed dim e
        bf16x4 pk = { (short)f2b(acc[mt][nt][0]), (short)f2b(acc[mt][nt][1]),
                      (short)f2b(acc[mt][nt][2]), (short)f2b(acc[mt][nt][3]) };
        *(bf16x4*)&vt[(size_t)(b * 1024 + gc) * 2048 + s] = pk;
      }
    }
  }
}

// ---------------------------------------------------------------------------
// Output projection: out = ctx * Wo^T + bo. ctx bf16 (ws), Wo/bo fp32,
// out fp32 (verified R9).
// ---------------------------------------------------------------------------
__global__ __launch_bounds__(256, 2) void gemm_out_kernel(
    const u16* __restrict__ ctx, const float* __restrict__ wo,
    const float* __restrict__ bo, float* __restrict__ out) {
  __shared__ __align__(16) u16 As[128 * 40];
  __shared__ __align__(16) u16 Bs[128 * 40];
  const int tid = threadIdx.x;
  const int m0 = blockIdx.x * 128;
  const int n0 = blockIdx.y * 128;

  f32x4 acc[4][4] = {};
  gemm_core<false>(ctx, wo, m0, n0, tid, As, Bs, acc);

  const int lane = tid & 63, wave = tid >> 6;
  const int wr = wave >> 1, wc = wave & 1;
  const int l15 = lane & 15, quad = lane >> 4;
#pragma unroll
  for (int nt = 0; nt < 4; ++nt) {
    const int gc = n0 + wc * 64 + nt * 16 + l15;
    const float bv = bo[gc];
#pragma unroll
    for (int mt = 0; mt < 4; ++mt) {
      const int gr = m0 + wr * 64 + mt * 16 + quad * 4;
#pragma unroll
      for (int r = 0; r < 4; ++r)
        out[(size_t)(gr + r) * 1024 + gc] = acc[mt][nt][r] + bv;
    }
  }
}

// ---------------------------------------------------------------------------
// Flash v4: 4-wave blocks, QBLK=64 (16 q-rows/wave), KVBLK=64.
// K,V tiles staged to LDS via global_load_lds (coalesced, shared 4x),
// double-buffered 2-phase pipeline; XOR-swizzled rows (chunk ^= row&7) so
// ds_read_b128 fragment reads spread across bank groups.
// Softmax identical math to v3 (C-layout swapped QK^T, per-wave P bounce,
// stride-72 conflict-free), LOG2E folded into the 1/8 scale.
// ctx aliases q: per-wave q-slices read at start == slices written at end.
// ---------------------------------------------------------------------------
__global__ __launch_bounds__(256, 3) void flash_kernel(
    const u16* q, const u16* __restrict__ k,
    const u16* __restrict__ vt, u16* ctx) {
  __shared__ __align__(16) u16 Ks[2][4096];       // [kv 64][d 64] swizzled
  __shared__ __align__(16) u16 Vs[2][4096];       // [d 64][kv 64] swizzled
  __shared__ __align__(16) u16 plds_all[4][16 * 72];

  const int tid = threadIdx.x;
  const int wave = tid >> 6, lane = tid & 63;
  const int l15 = lane & 15, quad = lane >> 4;
  const int q0b = (31 - (int)blockIdx.x) * 64;    // heavy-first LPT
  const int ntiles = 32 - (int)blockIdx.x;        // block-uniform!
  const int bh = blockIdx.y;
  const int b = bh >> 4, h = bh & 15;
  const int m = q0b + wave * 16 + l15;            // q-row this lane owns

  const u16* qrow = q + ((size_t)(b * 2048 + m) * 1024 + h * 64);
  const bf16x8 qf0 = *(const bf16x8*)(qrow + quad * 8);
  const bf16x8 qf1 = *(const bf16x8*)(qrow + 32 + quad * 8);

  // staging geometry: per thread 2 issues K + 2 issues V, 16B each.
  // dest byte o = wave*2048 + i*1024 + lane*16 -> row = wave*16+i*8+(lane>>3),
  // src chunk = dest chunk ^ (row&7)  (involution; row&7 == (lane>>3)&7).
  const int sr = wave * 16 + (lane >> 3);                 // + i*8
  const int csrc = (((lane & 7) ^ ((lane >> 3) & 7)) << 3);  // u16 offset
  const u16* kg = k + (size_t)(b * 2048) * 1024 + h * 64;
  const u16* vg = vt + (size_t)(b * 1024 + h * 64) * 2048;
  u16* plds = plds_all[wave];
  const int swz = (l15 & 7);                      // read-side row XOR

  f32x4 o[4] = {};
  float m_run = -INFINITY, l_run = 0.0f;

  // prologue: stage tile 0 into buf 0
#pragma unroll
  for (int i = 0; i < 2; ++i) {
    const int r = sr + i * 8;
    gl_lds16(kg + (size_t)r * 1024 + csrc, &Ks[0][wave * 1024 + i * 512]);
    gl_lds16(vg + (size_t)r * 2048 + csrc, &Vs[0][wave * 1024 + i * 512]);
  }
  __syncthreads();  // drains vmcnt(0) -> tile 0 resident

  int buf = 0;
  for (int t = 0; t < ntiles; ++t) {
    const int n0 = t * 64;
    // issue next-tile staging (overlaps with compute; drained at barrier)
    if (t + 1 < ntiles) {
      const int n1 = n0 + 64;
      const int nb = buf ^ 1;
#pragma unroll
      for (int i = 0; i < 2; ++i) {
        const int r = sr + i * 8;
        gl_lds16(kg + (size_t)(n1 + r) * 1024 + csrc,
                 &Ks[nb][wave * 1024 + i * 512]);
        gl_lds16(vg + (size_t)r * 2048 + n1 + csrc,
                 &Vs[nb][wave * 1024 + i * 512]);
      }
    }

    // ---- QK^T: st[s4] covers kv = n0 + s4*16 + quad*4 + r, q = l15 ----
    f32x4 st[4];
#pragma unroll
    for (int s4 = 0; s4 < 4; ++s4) {
      const u16* kr = &Ks[buf][(s4 * 16 + l15) * 64];
      const bf16x8 kf0 = *(const bf16x8*)(kr + ((quad ^ swz) << 3));
      const bf16x8 kf1 = *(const bf16x8*)(kr + (((4 | quad) ^ swz) << 3));
      f32x4 a = {};
      a = __builtin_amdgcn_mfma_f32_16x16x32_bf16(kf0, qf0, a, 0, 0, 0);
      a = __builtin_amdgcn_mfma_f32_16x16x32_bf16(kf1, qf1, a, 0, 0, 0);
      st[s4] = a;
    }

    // ---- softmax (log2 domain; scale = 0.125 * log2(e)) ----
    float s[16];
#pragma unroll
    for (int s4 = 0; s4 < 4; ++s4)
#pragma unroll
      for (int r = 0; r < 4; ++r) {
        const int kv = n0 + s4 * 16 + quad * 4 + r;
        const float v = st[s4][r] * (0.125f * LOG2E);
        s[s4 * 4 + r] = (kv > m) ? -INFINITY : v;
      }
    float t8[8], t4[4];
#pragma unroll
    for (int i = 0; i < 8; ++i) t8[i] = fmaxf(s[i], s[i + 8]);
#pragma unroll
    for (int i = 0; i < 4; ++i) t4[i] = fmaxf(t8[i], t8[i + 4]);
    float mx = fmaxf(fmaxf(t4[0], t4[1]), fmaxf(t4[2], t4[3]));
    mx = fmaxf(mx, __shfl_xor(mx, 16));
    mx = fmaxf(mx, __shfl_xor(mx, 32));
    const float m_new = fmaxf(m_run, mx);
    const float alpha = exp2f(m_run - m_new);  // 0 on first tile

    float p[16];
#pragma unroll
    for (int i = 0; i < 16; ++i) p[i] = exp2f(s[i] - m_new);
    float u8[8], u4[4];
#pragma unroll
    for (int i = 0; i < 8; ++i) u8[i] = p[i] + p[i + 8];
#pragma unroll
    for (int i = 0; i < 4; ++i) u4[i] = u8[i] + u8[i + 4];
    float sum = (u4[0] + u4[1]) + (u4[2] + u4[3]);
    sum += __shfl_xor(sum, 16);
    sum += __shfl_xor(sum, 32);
    l_run = l_run * alpha + sum;
    m_run = m_new;
#pragma unroll
    for (int dt = 0; dt < 4; ++dt) o[dt] *= alpha;

    // ---- P (C-layout) -> LDS [q][kv'] stride 72 -> B-layout frags ----
#pragma unroll
    for (int s4 = 0; s4 < 4; ++s4) {
      bf16x4 pk = { (short)f2b(p[s4 * 4 + 0]), (short)f2b(p[s4 * 4 + 1]),
                    (short)f2b(p[s4 * 4 + 2]), (short)f2b(p[s4 * 4 + 3]) };
      *(bf16x4*)&plds[l15 * 72 + s4 * 16 + quad * 4] = pk;
    }
    asm volatile("s_waitcnt lgkmcnt(0)" ::: "memory");

    // ---- PV: o[dt] row = d = dt*16 + quad*4 + r, col = q = l15 ----
#pragma unroll
    for (int ks = 0; ks < 2; ++ks) {
      const bf16x8 pf = *(const bf16x8*)&plds[l15 * 72 + ks * 32 + quad * 8];
#pragma unroll
      for (int dt = 0; dt < 4; ++dt) {
        const u16* vr = &Vs[buf][(dt * 16 + l15) * 64];
        const bf16x8 vf =
            *(const bf16x8*)(vr + ((((ks << 2) | quad) ^ swz) << 3));
        o[dt] = __builtin_amdgcn_mfma_f32_16x16x32_bf16(vf, pf, o[dt], 0, 0, 0);
      }
    }

    __syncthreads();  // drains vmcnt(0): next tile staged; buf safe to reuse
    buf ^= 1;
  }

  const float inv = 1.0f / l_run;
  u16* crow = ctx + ((size_t)(b * 2048 + m) * 1024 + h * 64);
#pragma unroll
  for (int dt = 0; dt < 4; ++dt) {
    bf16x4 ov = { (short)f2b(o[dt][0] * inv), (short)f2b(o[dt][1] * inv),
                  (short)f2b(o[dt][2] * inv), (short)f2b(o[dt][3] * inv) };
    *(bf16x4*)&crow[dt * 16 + quad * 4] = ov;
  }
}

// ---------------------------------------------------------------------------
extern "C" void kernel_launch(void* const* d_in, const int* in_sizes, int n_in,
                              void* d_out, int out_size, void* d_ws,
                              size_t ws_size, hipStream_t stream) {
  // Interface (R9-verified): inputs fp32 in dict order, output fp32.
  const float* x  = (const float*)d_in[0];
  const float* wq = (const float*)d_in[1];
  const float* wk = (const float*)d_in[2];
  const float* wv = (const float*)d_in[3];
  const float* wo = (const float*)d_in[4];
  const float* bo = (const float*)d_in[5];
  float* out = (float*)d_out;

  // ws (bf16 elems): qb [0,4M) (aliased as ctx), kb [4M,8M),
  // vt [8M,12M) transposed V. 24 MiB.
  u16* qb = (u16*)d_ws;
  u16* kb = qb + 4194304u;
  u16* vt = kb + 4194304u;
  u16* ctx = qb;

  gemm_qkv_kernel<<<dim3(32, 24), 256, 0, stream>>>(x, wq, wk, wv, qb, kb, vt);
  flash_kernel<<<dim3(32, 32), 256, 0, stream>>>(qb, kb, vt, ctx);
  gemm_out_kernel<<<dim3(32, 8), 256, 0, stream>>>(ctx, wo, bo, out);
}

// Round 2
// 210.718 us; speedup vs baseline: 1.8256x; 1.2295x over previous
//
#include <hip/hip_runtime.h>

typedef unsigned short u16;
typedef unsigned int u32;
typedef short bf16x8 __attribute__((ext_vector_type(8)));
typedef short bf16x4 __attribute__((ext_vector_type(4)));
typedef float f32x4 __attribute__((ext_vector_type(4)));
typedef u32 u32x2 __attribute__((ext_vector_type(2)));

#define LOG2E 1.4426950408889634f
#define QSCALE (0.125f * LOG2E)   // folded into Q at QKV epilogue

__device__ __forceinline__ u16 f2b(float f) {
  u32 u = __builtin_bit_cast(u32, f);
  u32 r = (u + 0x7FFFu + ((u >> 16) & 1u)) >> 16;
  return (u16)r;
}

// 8 consecutive elements as bf16x8; F32 selects fp32-source (convert) vs bf16.
template <bool F32>
__device__ __forceinline__ bf16x8 load8(const void* base, size_t idx) {
  if (F32) {
    const float* p = (const float*)base + idx;
    const f32x4 a = *(const f32x4*)p;
    const f32x4 b = *(const f32x4*)(p + 4);
    bf16x8 r = { (short)f2b(a[0]), (short)f2b(a[1]), (short)f2b(a[2]),
                 (short)f2b(a[3]), (short)f2b(b[0]), (short)f2b(b[1]),
                 (short)f2b(b[2]), (short)f2b(b[3]) };
    return r;
  }
  return *(const bf16x8*)((const u16*)base + idx);
}

// async global->LDS, 16B per lane; lds dest must be wave-uniform base.
__device__ __forceinline__ void gl_lds16(const u16* g, u16* l) {
  __builtin_amdgcn_global_load_lds(
      (const __attribute__((address_space(1))) u32*)(const void*)g,
      (__attribute__((address_space(3))) u32*)(void*)l, 16, 0, 0);
}

// ---------------------------------------------------------------------------
// fp32 -> bf16 one-shot converts (operand pre-pass; x+Wq/Wk/Wv live in d_out
// scratch, which is dead until gemm_out writes the real output).
// ---------------------------------------------------------------------------
__global__ __launch_bounds__(256) void convert_qw_kernel(
    const float* __restrict__ x, const float* __restrict__ wq,
    const float* __restrict__ wk, const float* __restrict__ wv,
    u16* __restrict__ xb, u16* __restrict__ wb) {
  const int i = blockIdx.x * 256 + threadIdx.x;
  if (i >= 917504) return;  // 524288 (x) + 3*131072 (w)
  const float* src;
  u16* dst;
  size_t off;
  if (i < 524288) {
    src = x; dst = xb; off = (size_t)i * 8;
  } else {
    const int j = i - 524288;
    const int mat = j >> 17, r = j & 131071;
    src = (mat == 0) ? wq : ((mat == 1) ? wk : wv);
    dst = wb + (size_t)mat * 1048576u;
    off = (size_t)r * 8;
  }
  *(bf16x8*)(dst + off) = load8<true>(src, off);
}

__global__ __launch_bounds__(256) void convert_wo_kernel(
    const float* __restrict__ wo, u16* __restrict__ wob) {
  const int i = blockIdx.x * 256 + threadIdx.x;
  if (i >= 131072) return;
  const size_t off = (size_t)i * 8;
  *(bf16x8*)(wob + off) = load8<true>(wo, off);
}

// ---------------------------------------------------------------------------
// NT GEMM core (R9-verified structure): C[128x128] += A * W^T, K=1024.
// Both operands bf16 now (pre-converted) -> staging is pure b128 copy.
// ---------------------------------------------------------------------------
template <bool AF32, bool WF32>
__device__ __forceinline__ void gemm_core(const void* A, const void* W,
                                          int m0, int n0, int tid,
                                          u16* As, u16* Bs,
                                          f32x4 (&acc)[4][4]) {
  const int lane = tid & 63, wave = tid >> 6;
  const int wr = wave >> 1, wc = wave & 1;
  const int l15 = lane & 15, quad = lane >> 4;
  const int r0 = tid >> 2;
  const int c8 = (tid & 3) << 3;

  const size_t ia0 = (size_t)(m0 + r0) * 1024 + c8;
  const size_t ia1 = ia0 + (size_t)64 * 1024;
  const size_t iw0 = (size_t)(n0 + r0) * 1024 + c8;
  const size_t iw1 = iw0 + (size_t)64 * 1024;

  u16* sa0 = As + r0 * 40 + c8;
  u16* sa1 = sa0 + 64 * 40;
  u16* sb0 = Bs + r0 * 40 + c8;
  u16* sb1 = sb0 + 64 * 40;

  const u16* ar = As + (wr * 64 + l15) * 40 + quad * 8;
  const u16* br = Bs + (wc * 64 + l15) * 40 + quad * 8;

  bf16x8 ra0 = load8<AF32>(A, ia0);
  bf16x8 ra1 = load8<AF32>(A, ia1);
  bf16x8 rw0 = load8<WF32>(W, iw0);
  bf16x8 rw1 = load8<WF32>(W, iw1);

  for (int k0 = 0; k0 < 1024; k0 += 32) {
    *(bf16x8*)sa0 = ra0;
    *(bf16x8*)sa1 = ra1;
    *(bf16x8*)sb0 = rw0;
    *(bf16x8*)sb1 = rw1;
    __syncthreads();
    if (k0 + 32 < 1024) {
      ra0 = load8<AF32>(A, ia0 + k0 + 32);
      ra1 = load8<AF32>(A, ia1 + k0 + 32);
      rw0 = load8<WF32>(W, iw0 + k0 + 32);
      rw1 = load8<WF32>(W, iw1 + k0 + 32);
    }
    bf16x8 af[4], bfr[4];
#pragma unroll
    for (int i = 0; i < 4; ++i) af[i] = *(const bf16x8*)(ar + i * 16 * 40);
#pragma unroll
    for (int i = 0; i < 4; ++i) bfr[i] = *(const bf16x8*)(br + i * 16 * 40);
#pragma unroll
    for (int mt = 0; mt < 4; ++mt)
#pragma unroll
      for (int nt = 0; nt < 4; ++nt)
        acc[mt][nt] = __builtin_amdgcn_mfma_f32_16x16x32_bf16(
            af[mt], bfr[nt], acc[mt][nt], 0, 0, 0);
    __syncthreads();
  }
}

// ---------------------------------------------------------------------------
// Fused QKV projection (bf16 in, bf16 out). Q is pre-scaled by 0.125*log2e
// so flash's scores come out of MFMA already in log2 domain.
// V transposed: vt[(b*1024+e)*2048 + s]. blockIdx.y: [0..7]=Q, [8..15]=K,
// [16..23]=V.
// ---------------------------------------------------------------------------
__global__ __launch_bounds__(256, 2) void gemm_qkv_kernel(
    const u16* __restrict__ xb, const u16* __restrict__ wb,
    u16* __restrict__ qo, u16* __restrict__ ko, u16* __restrict__ vt) {
  __shared__ __align__(16) u16 As[128 * 40];
  __shared__ __align__(16) u16 Bs[128 * 40];
  const int tid = threadIdx.x;
  const int m0 = blockIdx.x * 128;
  const int mat = blockIdx.y >> 3;
  const int n0 = (blockIdx.y & 7) * 128;
  const u16* W = wb + (size_t)mat * 1048576u;

  f32x4 acc[4][4] = {};
  gemm_core<false, false>(xb, W, m0, n0, tid, As, Bs, acc);

  const int lane = tid & 63, wave = tid >> 6;
  const int wr = wave >> 1, wc = wave & 1;
  const int l15 = lane & 15, quad = lane >> 4;

  if (mat < 2) {
    u16* out = (mat == 0) ? qo : ko;
    const float sc = (mat == 0) ? QSCALE : 1.0f;
#pragma unroll
    for (int mt = 0; mt < 4; ++mt) {
      const int gr = m0 + wr * 64 + mt * 16 + quad * 4;
#pragma unroll
      for (int nt = 0; nt < 4; ++nt) {
        const int gc = n0 + wc * 64 + nt * 16 + l15;
#pragma unroll
        for (int r = 0; r < 4; ++r)
          out[(size_t)(gr + r) * 1024 + gc] = f2b(acc[mt][nt][r] * sc);
      }
    }
  } else {
    // vt[(b*1024 + e)*2048 + s]; 4 consecutive s per lane -> 8B store
#pragma unroll
    for (int mt = 0; mt < 4; ++mt) {
      const int gr = m0 + wr * 64 + mt * 16 + quad * 4;  // token idx b*2048+s
      const int b = gr >> 11;
      const int s = gr & 2047;
#pragma unroll
      for (int nt = 0; nt < 4; ++nt) {
        const int gc = n0 + wc * 64 + nt * 16 + l15;     // embed dim e
        bf16x4 pk = { (short)f2b(acc[mt][nt][0]), (short)f2b(acc[mt][nt][1]),
                      (short)f2b(acc[mt][nt][2]), (short)f2b(acc[mt][nt][3]) };
        *(bf16x4*)&vt[(size_t)(b * 1024 + gc) * 2048 + s] = pk;
      }
    }
  }
}

// ---------------------------------------------------------------------------
// Output projection: out = ctx * Wo^T + bo. ctx bf16, Wo bf16 (pre-converted
// into kb region, dead after flash), bo fp32, out fp32.
// ---------------------------------------------------------------------------
__global__ __launch_bounds__(256, 2) void gemm_out_kernel(
    const u16* __restrict__ ctx, const u16* __restrict__ wob,
    const float* __restrict__ bo, float* __restrict__ out) {
  __shared__ __align__(16) u16 As[128 * 40];
  __shared__ __align__(16) u16 Bs[128 * 40];
  const int tid = threadIdx.x;
  const int m0 = blockIdx.x * 128;
  const int n0 = blockIdx.y * 128;

  f32x4 acc[4][4] = {};
  gemm_core<false, false>(ctx, wob, m0, n0, tid, As, Bs, acc);

  const int lane = tid & 63, wave = tid >> 6;
  const int wr = wave >> 1, wc = wave & 1;
  const int l15 = lane & 15, quad = lane >> 4;
#pragma unroll
  for (int nt = 0; nt < 4; ++nt) {
    const int gc = n0 + wc * 64 + nt * 16 + l15;
    const float bv = bo[gc];
#pragma unroll
    for (int mt = 0; mt < 4; ++mt) {
      const int gr = m0 + wr * 64 + mt * 16 + quad * 4;
#pragma unroll
      for (int r = 0; r < 4; ++r)
        out[(size_t)(gr + r) * 1024 + gc] = acc[mt][nt][r] + bv;
    }
  }
}

// ---------------------------------------------------------------------------
// Flash v5: v4 structure (4-wave, KVBLK=64, gl_lds staged K/V, 2-phase
// double buffer) + VALU diet:
//  - Q pre-scaled (no per-score mul); scores already log2-domain
//  - causal mask applied ONLY on the diagonal tile (provably t==ntiles-1)
//  - defer-max THR=8 (skip alpha rescale when max doesn't grow)
//  - lane-local l accumulation; single cross-lane reduce at the end
//  - P pack via v_cvt_pk_bf16_f32 (8 insts vs ~64 bit-twiddle)
//  - P scratch: stride-64 + chunk XOR swizzle (chunk^=(l15&7)) -> LDS total
//    exactly 40960 B -> 4 blocks/CU; __launch_bounds__(256,4)
// ctx aliases q: per-wave q-slices read at start == slices written at end.
// ---------------------------------------------------------------------------
__global__ __launch_bounds__(256, 4) void flash_kernel(
    const u16* q, const u16* __restrict__ k,
    const u16* __restrict__ vt, u16* ctx) {
  __shared__ __align__(16) u16 Ks[2][4096];       // [kv 64][d 64] swizzled
  __shared__ __align__(16) u16 Vs[2][4096];       // [d 64][kv 64] swizzled
  __shared__ __align__(16) u16 plds_all[4][1024]; // [wave][16 q][64 kv] swz

  const int tid = threadIdx.x;
  const int wave = tid >> 6, lane = tid & 63;
  const int l15 = lane & 15, quad = lane >> 4;
  const int q0b = (31 - (int)blockIdx.x) * 64;    // heavy-first LPT
  const int ntiles = 32 - (int)blockIdx.x;        // block-uniform
  const int bh = blockIdx.y;
  const int b = bh >> 4, h = bh & 15;
  const int m = q0b + wave * 16 + l15;            // q-row this lane owns

  const u16* qrow = q + ((size_t)(b * 2048 + m) * 1024 + h * 64);
  const bf16x8 qf0 = *(const bf16x8*)(qrow + quad * 8);
  const bf16x8 qf1 = *(const bf16x8*)(qrow + 32 + quad * 8);

  // staging: per thread 2 issues K + 2 issues V, 16B each; LDS dest linear,
  // global src pre-swizzled by (row&7) chunk XOR (involution).
  const int sr = wave * 16 + (lane >> 3);                    // + i*8
  const int csrc = (((lane & 7) ^ ((lane >> 3) & 7)) << 3);  // u16 offset
  const u16* kg = k + (size_t)(b * 2048) * 1024 + h * 64;
  const u16* vg = vt + (size_t)(b * 1024 + h * 64) * 2048;
  u16* plds = plds_all[wave];
  const int swz = (l15 & 7);                      // read-side row XOR

  f32x4 o[4] = {};
  float m_run = -INFINITY, l_lane = 0.0f;

  // prologue: stage tile 0 into buf 0
#pragma unroll
  for (int i = 0; i < 2; ++i) {
    const int r = sr + i * 8;
    gl_lds16(kg + (size_t)r * 1024 + csrc, &Ks[0][wave * 1024 + i * 512]);
    gl_lds16(vg + (size_t)r * 2048 + csrc, &Vs[0][wave * 1024 + i * 512]);
  }
  __syncthreads();  // drains vmcnt(0) -> tile 0 resident

  int buf = 0;
  for (int t = 0; t < ntiles; ++t) {
    const int n0 = t * 64;
    // issue next-tile staging (overlaps with compute; drained at barrier)
    if (t + 1 < ntiles) {
      const int n1 = n0 + 64;
      const int nb = buf ^ 1;
#pragma unroll
      for (int i = 0; i < 2; ++i) {
        const int r = sr + i * 8;
        gl_lds16(kg + (size_t)(n1 + r) * 1024 + csrc,
                 &Ks[nb][wave * 1024 + i * 512]);
        gl_lds16(vg + (size_t)r * 2048 + n1 + csrc,
                 &Vs[nb][wave * 1024 + i * 512]);
      }
    }

    // ---- QK^T: st[s4] covers kv = n0 + s4*16 + quad*4 + r, q = l15 ----
    f32x4 st[4];
#pragma unroll
    for (int s4 = 0; s4 < 4; ++s4) {
      const u16* kr = &Ks[buf][(s4 * 16 + l15) * 64];
      const bf16x8 kf0 = *(const bf16x8*)(kr + ((quad ^ swz) << 3));
      const bf16x8 kf1 = *(const bf16x8*)(kr + (((4 | quad) ^ swz) << 3));
      f32x4 a = {};
      a = __builtin_amdgcn_mfma_f32_16x16x32_bf16(kf0, qf0, a, 0, 0, 0);
      a = __builtin_amdgcn_mfma_f32_16x16x32_bf16(kf1, qf1, a, 0, 0, 0);
      st[s4] = a;
    }

    // ---- softmax (scores already in log2 domain via pre-scaled Q) ----
    float s[16];
#pragma unroll
    for (int s4 = 0; s4 < 4; ++s4)
#pragma unroll
      for (int r = 0; r < 4; ++r) s[s4 * 4 + r] = st[s4][r];
    if (t == ntiles - 1) {  // diagonal tile: the only one needing the mask
#pragma unroll
      for (int s4 = 0; s4 < 4; ++s4)
#pragma unroll
        for (int r = 0; r < 4; ++r) {
          const int kv = n0 + s4 * 16 + quad * 4 + r;
          if (kv > m) s[s4 * 4 + r] = -INFINITY;
        }
    }
    float t8[8], t4[4];
#pragma unroll
    for (int i = 0; i < 8; ++i) t8[i] = fmaxf(s[i], s[i + 8]);
#pragma unroll
    for (int i = 0; i < 4; ++i) t4[i] = fmaxf(t8[i], t8[i + 4]);
    float mx = fmaxf(fmaxf(t4[0], t4[1]), fmaxf(t4[2], t4[3]));
    mx = fmaxf(mx, __shfl_xor(mx, 16));
    mx = fmaxf(mx, __shfl_xor(mx, 32));

    float mbase;
    if (__all(mx <= m_run + 8.0f)) {
      mbase = m_run;                     // defer: P bounded by 2^8, bf16-safe
    } else {
      mbase = fmaxf(m_run, mx);
      const float alpha = exp2f(m_run - mbase);  // 0 on first tile
      l_lane *= alpha;
#pragma unroll
      for (int dt = 0; dt < 4; ++dt) o[dt] *= alpha;
      m_run = mbase;
    }

    float p[16];
#pragma unroll
    for (int i = 0; i < 16; ++i) p[i] = exp2f(s[i] - mbase);
    float u8[8], u4[4];
#pragma unroll
    for (int i = 0; i < 8; ++i) u8[i] = p[i] + p[i + 8];
#pragma unroll
    for (int i = 0; i < 4; ++i) u4[i] = u8[i] + u8[i + 4];
    l_lane += (u4[0] + u4[1]) + (u4[2] + u4[3]);  // lane-local; reduce at end

    // ---- P -> LDS, stride 64 + chunk XOR swizzle; cvt_pk packing ----
#pragma unroll
    for (int s4 = 0; s4 < 4; ++s4) {
      u32 c0, c1;
      asm("v_cvt_pk_bf16_f32 %0, %1, %2"
          : "=v"(c0) : "v"(p[s4 * 4 + 0]), "v"(p[s4 * 4 + 1]));
      asm("v_cvt_pk_bf16_f32 %0, %1, %2"
          : "=v"(c1) : "v"(p[s4 * 4 + 2]), "v"(p[s4 * 4 + 3]));
      const int wchunk = ((s4 * 2 + (quad >> 1)) ^ swz) << 3;
      u32x2 w = { c0, c1 };
      *(u32x2*)&plds[l15 * 64 + wchunk + ((quad & 1) << 2)] = w;
    }
    asm volatile("s_waitcnt lgkmcnt(0)" ::: "memory");

    // ---- PV: o[dt] row = d = dt*16 + quad*4 + r, col = q = l15 ----
#pragma unroll
    for (int ks = 0; ks < 2; ++ks) {
      const bf16x8 pf =
          *(const bf16x8*)&plds[l15 * 64 + (((ks * 4 + quad) ^ swz) << 3)];
#pragma unroll
      for (int dt = 0; dt < 4; ++dt) {
        const u16* vr = &Vs[buf][(dt * 16 + l15) * 64];
        const bf16x8 vf =
            *(const bf16x8*)(vr + ((((ks << 2) | quad) ^ swz) << 3));
        o[dt] = __builtin_amdgcn_mfma_f32_16x16x32_bf16(vf, pf, o[dt], 0, 0, 0);
      }
    }

    __syncthreads();  // drains vmcnt(0): next tile staged; buf safe to reuse
    buf ^= 1;
  }

  float l = l_lane;
  l += __shfl_xor(l, 16);
  l += __shfl_xor(l, 32);
  const float inv = 1.0f / l;
  u16* crow = ctx + ((size_t)(b * 2048 + m) * 1024 + h * 64);
#pragma unroll
  for (int dt = 0; dt < 4; ++dt) {
    bf16x4 ov = { (short)f2b(o[dt][0] * inv), (short)f2b(o[dt][1] * inv),
                  (short)f2b(o[dt][2] * inv), (short)f2b(o[dt][3] * inv) };
    *(bf16x4*)&crow[dt * 16 + quad * 4] = ov;
  }
}

// ---------------------------------------------------------------------------
extern "C" void kernel_launch(void* const* d_in, const int* in_sizes, int n_in,
                              void* d_out, int out_size, void* d_ws,
                              size_t ws_size, hipStream_t stream) {
  // Interface (R9-verified): inputs fp32 in dict order, output fp32.
  const float* x  = (const float*)d_in[0];
  const float* wq = (const float*)d_in[1];
  const float* wk = (const float*)d_in[2];
  const float* wv = (const float*)d_in[3];
  const float* wo = (const float*)d_in[4];
  const float* bo = (const float*)d_in[5];
  float* out = (float*)d_out;

  // ws (bf16 elems): qb [0,4M) (aliased as ctx), kb [4M,8M),
  // vt [8M,12M) transposed V. 24 MiB.
  u16* qb = (u16*)d_ws;
  u16* kb = qb + 4194304u;
  u16* vt = kb + 4194304u;
  u16* ctx = qb;

  // d_out doubles as pre-converted-operand scratch until gemm_out runs:
  // xb [0, 8MiB) = x in bf16; wb [8, 14MiB) = Wq|Wk|Wv in bf16. (out is
  // 16 MiB fp32; nothing reads it before gemm_out writes the real result.)
  u16* xb = (u16*)d_out;
  u16* wb = xb + 4194304u;
  // Wo bf16 goes into kb, which is dead after flash_kernel.
  u16* wob = kb;

  convert_qw_kernel<<<3584, 256, 0, stream>>>(x, wq, wk, wv, xb, wb);
  gemm_qkv_kernel<<<dim3(32, 24), 256, 0, stream>>>(xb, wb, qb, kb, vt);
  flash_kernel<<<dim3(32, 32), 256, 0, stream>>>(qb, kb, vt, ctx);
  convert_wo_kernel<<<512, 256, 0, stream>>>(wo, wob);
  gemm_out_kernel<<<dim3(32, 8), 256, 0, stream>>>(ctx, wob, bo, out);
}

// Round 3
// 191.747 us; speedup vs baseline: 2.0062x; 1.0989x over previous
//
#include <hip/hip_runtime.h>

typedef unsigned short u16;
typedef unsigned int u32;
typedef short bf16x8 __attribute__((ext_vector_type(8)));
typedef short bf16x4 __attribute__((ext_vector_type(4)));
typedef float f32x4 __attribute__((ext_vector_type(4)));
typedef u32 u32x2 __attribute__((ext_vector_type(2)));

#define LOG2E 1.4426950408889634f
#define QSCALE (0.125f * LOG2E)   // folded into Q at QKV epilogue

__device__ __forceinline__ u16 f2b(float f) {
  u32 u = __builtin_bit_cast(u32, f);
  u32 r = (u + 0x7FFFu + ((u >> 16) & 1u)) >> 16;
  return (u16)r;
}

// 8 consecutive fp32 -> bf16x8 (convert kernels only now)
__device__ __forceinline__ bf16x8 cvt8(const float* p) {
  const f32x4 a = *(const f32x4*)p;
  const f32x4 b = *(const f32x4*)(p + 4);
  bf16x8 r = { (short)f2b(a[0]), (short)f2b(a[1]), (short)f2b(a[2]),
               (short)f2b(a[3]), (short)f2b(b[0]), (short)f2b(b[1]),
               (short)f2b(b[2]), (short)f2b(b[3]) };
  return r;
}

// async global->LDS, 16B per lane; lds dest must be wave-uniform base.
__device__ __forceinline__ void gl_lds16(const u16* g, u16* l) {
  __builtin_amdgcn_global_load_lds(
      (const __attribute__((address_space(1))) u32*)(const void*)g,
      (__attribute__((address_space(3))) u32*)(void*)l, 16, 0, 0);
}

// ---------------------------------------------------------------------------
// fp32 -> bf16 one-shot converts (x+Wq/Wk/Wv into d_out scratch, dead until
// gemm_out writes the real output; Wo into kb after flash).
// ---------------------------------------------------------------------------
__global__ __launch_bounds__(256) void convert_qw_kernel(
    const float* __restrict__ x, const float* __restrict__ wq,
    const float* __restrict__ wk, const float* __restrict__ wv,
    u16* __restrict__ xb, u16* __restrict__ wb) {
  const int i = blockIdx.x * 256 + threadIdx.x;
  if (i >= 917504) return;  // 524288 (x) + 3*131072 (w)
  const float* src;
  u16* dst;
  size_t off;
  if (i < 524288) {
    src = x; dst = xb; off = (size_t)i * 8;
  } else {
    const int j = i - 524288;
    const int mat = j >> 17, r = j & 131071;
    src = (mat == 0) ? wq : ((mat == 1) ? wk : wv);
    dst = wb + (size_t)mat * 1048576u;
    off = (size_t)r * 8;
  }
  *(bf16x8*)(dst + off) = cvt8(src + off);
}

__global__ __launch_bounds__(256) void convert_wo_kernel(
    const float* __restrict__ wo, u16* __restrict__ wob) {
  const int i = blockIdx.x * 256 + threadIdx.x;
  if (i >= 131072) return;
  const size_t off = (size_t)i * 8;
  *(bf16x8*)(wob + off) = cvt8(wo + off);
}

// ---------------------------------------------------------------------------
// NT GEMM core v2 (m97 structure): C[128x128] += A * W^T, K=1024, BK=32.
// global_load_lds direct staging; LDS linear [128][32] u16 with 16B-chunk
// XOR swizzle  chunk ^= (row&3)^((row>>2)&3)  applied on the pre-swizzled
// global source AND the fragment read (both-sides-or-neither) -> fragment
// ds_read_b128 lands each 16B bank-slot exactly 2x (conflict-free).
// ---------------------------------------------------------------------------
__device__ __forceinline__ void gemm_core2(const u16* A, const u16* W,
                                           int m0, int n0, int tid,
                                           u16* As, u16* Bs,
                                           f32x4 (&acc)[4][4]) {
  const int lane = tid & 63, wave = tid >> 6;
  const int wr = wave >> 1, wc = wave & 1;
  const int l15 = lane & 15, quad = lane >> 4;

  // staging: instr i in {0,1} covers local rows i*64 + wave*16 + (lane>>2),
  // chunk lane&3 at dest; source chunk pre-swizzled (lane-only expression).
  const int srow = wave * 16 + (lane >> 2);                  // + i*64
  const int csrc =
      (((lane & 3) ^ ((lane >> 2) & 3) ^ ((lane >> 4) & 3)) << 3);  // u16
  const u16* ga = A + (size_t)(m0 + srow) * 1024 + csrc;
  const u16* gw = W + (size_t)(n0 + srow) * 1024 + csrc;
  u16* la = As + wave * 16 * 32;                             // + i*64*32
  u16* lb = Bs + wave * 16 * 32;

  // fragment read: row = (wr*64 + mt*16) + l15, chunk = quad ^ rswz(l15)
  const int rswz = (l15 & 3) ^ ((l15 >> 2) & 3);
  const u16* ar = As + (wr * 64 + l15) * 32 + ((quad ^ rswz) << 3);
  const u16* br = Bs + (wc * 64 + l15) * 32 + ((quad ^ rswz) << 3);

  for (int k0 = 0; k0 < 1024; k0 += 32) {
    __syncthreads();  // previous tile's readers done; LDS safe to overwrite
    gl_lds16(ga + k0, la);
    gl_lds16(ga + k0 + (size_t)64 * 1024, la + 64 * 32);
    gl_lds16(gw + k0, lb);
    gl_lds16(gw + k0 + (size_t)64 * 1024, lb + 64 * 32);
    __syncthreads();  // vmcnt(0) drained in barrier -> tile resident
    bf16x8 af[4], bfr[4];
#pragma unroll
    for (int i = 0; i < 4; ++i) af[i] = *(const bf16x8*)(ar + i * 16 * 32);
#pragma unroll
    for (int i = 0; i < 4; ++i) bfr[i] = *(const bf16x8*)(br + i * 16 * 32);
#pragma unroll
    for (int mt = 0; mt < 4; ++mt)
#pragma unroll
      for (int nt = 0; nt < 4; ++nt)
        acc[mt][nt] = __builtin_amdgcn_mfma_f32_16x16x32_bf16(
            af[mt], bfr[nt], acc[mt][nt], 0, 0, 0);
  }
}

// ---------------------------------------------------------------------------
// Fused QKV projection (bf16 in, bf16 out). Q pre-scaled by 0.125*log2e.
// V transposed: vt[(b*1024+e)*2048 + s]. blockIdx.y: [0..7]=Q, [8..15]=K,
// [16..23]=V.
// ---------------------------------------------------------------------------
__global__ __launch_bounds__(256, 3) void gemm_qkv_kernel(
    const u16* __restrict__ xb, const u16* __restrict__ wb,
    u16* __restrict__ qo, u16* __restrict__ ko, u16* __restrict__ vt) {
  __shared__ __align__(16) u16 As[128 * 32];
  __shared__ __align__(16) u16 Bs[128 * 32];
  const int tid = threadIdx.x;
  const int m0 = blockIdx.x * 128;
  const int mat = blockIdx.y >> 3;
  const int n0 = (blockIdx.y & 7) * 128;
  const u16* W = wb + (size_t)mat * 1048576u;

  f32x4 acc[4][4] = {};
  gemm_core2(xb, W, m0, n0, tid, As, Bs, acc);

  const int lane = tid & 63, wave = tid >> 6;
  const int wr = wave >> 1, wc = wave & 1;
  const int l15 = lane & 15, quad = lane >> 4;

  if (mat < 2) {
    u16* out = (mat == 0) ? qo : ko;
    const float sc = (mat == 0) ? QSCALE : 1.0f;
#pragma unroll
    for (int mt = 0; mt < 4; ++mt) {
      const int gr = m0 + wr * 64 + mt * 16 + quad * 4;
#pragma unroll
      for (int nt = 0; nt < 4; ++nt) {
        const int gc = n0 + wc * 64 + nt * 16 + l15;
#pragma unroll
        for (int r = 0; r < 4; ++r)
          out[(size_t)(gr + r) * 1024 + gc] = f2b(acc[mt][nt][r] * sc);
      }
    }
  } else {
    // vt[(b*1024 + e)*2048 + s]; 4 consecutive s per lane -> 8B store
#pragma unroll
    for (int mt = 0; mt < 4; ++mt) {
      const int gr = m0 + wr * 64 + mt * 16 + quad * 4;  // token idx b*2048+s
      const int b = gr >> 11;
      const int s = gr & 2047;
#pragma unroll
      for (int nt = 0; nt < 4; ++nt) {
        const int gc = n0 + wc * 64 + nt * 16 + l15;     // embed dim e
        bf16x4 pk = { (short)f2b(acc[mt][nt][0]), (short)f2b(acc[mt][nt][1]),
                      (short)f2b(acc[mt][nt][2]), (short)f2b(acc[mt][nt][3]) };
        *(bf16x4*)&vt[(size_t)(b * 1024 + gc) * 2048 + s] = pk;
      }
    }
  }
}

// ---------------------------------------------------------------------------
// Output projection: out = ctx * Wo^T + bo. ctx bf16, Wo bf16 (in kb, dead
// after flash), bo fp32, out fp32.
// ---------------------------------------------------------------------------
__global__ __launch_bounds__(256, 3) void gemm_out_kernel(
    const u16* __restrict__ ctx, const u16* __restrict__ wob,
    const float* __restrict__ bo, float* __restrict__ out) {
  __shared__ __align__(16) u16 As[128 * 32];
  __shared__ __align__(16) u16 Bs[128 * 32];
  const int tid = threadIdx.x;
  const int m0 = blockIdx.x * 128;
  const int n0 = blockIdx.y * 128;

  f32x4 acc[4][4] = {};
  gemm_core2(ctx, wob, m0, n0, tid, As, Bs, acc);

  const int lane = tid & 63, wave = tid >> 6;
  const int wr = wave >> 1, wc = wave & 1;
  const int l15 = lane & 15, quad = lane >> 4;
#pragma unroll
  for (int nt = 0; nt < 4; ++nt) {
    const int gc = n0 + wc * 64 + nt * 16 + l15;
    const float bv = bo[gc];
#pragma unroll
    for (int mt = 0; mt < 4; ++mt) {
      const int gr = m0 + wr * 64 + mt * 16 + quad * 4;
#pragma unroll
      for (int r = 0; r < 4; ++r)
        out[(size_t)(gr + r) * 1024 + gc] = acc[mt][nt][r] + bv;
    }
  }
}

// ---------------------------------------------------------------------------
// Flash v6 = v5 + XCD capacity clustering.
// 1-D grid of 1024 blocks. xcd = g&7 (HW round-robin); each XCD owns exactly
// 4 bh = {xcd, xcd+8, xcd+16, xcd+24} -> its K/V working set = 4 x 512 KB
// = 2 MB, L2-resident (was 16 MB thrash). Within an XCD, snake-pair q-ranks
// (c with 31-c) so under round-robin CU assignment each CU's 4 resident
// blocks sum to exactly 66 tile-iters (flat load, no LPT tail).
// ctx aliases q: per-wave q-slices read at start == slices written at end.
// ---------------------------------------------------------------------------
__global__ __launch_bounds__(256, 4) void flash_kernel(
    const u16* q, const u16* __restrict__ k,
    const u16* __restrict__ vt, u16* ctx) {
  __shared__ __align__(16) u16 Ks[2][4096];       // [kv 64][d 64] swizzled
  __shared__ __align__(16) u16 Vs[2][4096];       // [d 64][kv 64] swizzled
  __shared__ __align__(16) u16 plds_all[4][1024]; // [wave][16 q][64 kv] swz

  const int tid = threadIdx.x;
  const int wave = tid >> 6, lane = tid & 63;
  const int l15 = lane & 15, quad = lane >> 4;

  // ---- XCD-clustered block mapping ----
  const int g = blockIdx.x;
  const int xcd = g & 7;
  const int s = g >> 3;            // 0..127 within XCD
  const int bh_local = s >> 5;     // 0..3
  const int c = s & 31;
  const int qv = (bh_local & 1) ? (31 - c) : c;   // snake: CU sums = 66
  const int q0b = qv * 64;
  const int ntiles = qv + 1;       // block-uniform
  const int bh = xcd + 8 * bh_local;
  const int b = bh >> 4, h = bh & 15;
  const int m = q0b + wave * 16 + l15;            // q-row this lane owns

  const u16* qrow = q + ((size_t)(b * 2048 + m) * 1024 + h * 64);
  const bf16x8 qf0 = *(const bf16x8*)(qrow + quad * 8);
  const bf16x8 qf1 = *(const bf16x8*)(qrow + 32 + quad * 8);

  // staging: per thread 2 issues K + 2 issues V, 16B each; LDS dest linear,
  // global src pre-swizzled by (row&7) chunk XOR (involution).
  const int sr = wave * 16 + (lane >> 3);                    // + i*8
  const int csrc = (((lane & 7) ^ ((lane >> 3) & 7)) << 3);  // u16 offset
  const u16* kg = k + (size_t)(b * 2048) * 1024 + h * 64;
  const u16* vg = vt + (size_t)(b * 1024 + h * 64) * 2048;
  u16* plds = plds_all[wave];
  const int swz = (l15 & 7);                      // read-side row XOR

  f32x4 o[4] = {};
  float m_run = -INFINITY, l_lane = 0.0f;

  // prologue: stage tile 0 into buf 0
#pragma unroll
  for (int i = 0; i < 2; ++i) {
    const int r = sr + i * 8;
    gl_lds16(kg + (size_t)r * 1024 + csrc, &Ks[0][wave * 1024 + i * 512]);
    gl_lds16(vg + (size_t)r * 2048 + csrc, &Vs[0][wave * 1024 + i * 512]);
  }
  __syncthreads();  // drains vmcnt(0) -> tile 0 resident

  int buf = 0;
  for (int t = 0; t < ntiles; ++t) {
    const int n0 = t * 64;
    // issue next-tile staging (overlaps with compute; drained at barrier)
    if (t + 1 < ntiles) {
      const int n1 = n0 + 64;
      const int nb = buf ^ 1;
#pragma unroll
      for (int i = 0; i < 2; ++i) {
        const int r = sr + i * 8;
        gl_lds16(kg + (size_t)(n1 + r) * 1024 + csrc,
                 &Ks[nb][wave * 1024 + i * 512]);
        gl_lds16(vg + (size_t)r * 2048 + n1 + csrc,
                 &Vs[nb][wave * 1024 + i * 512]);
      }
    }

    // ---- QK^T: st[s4] covers kv = n0 + s4*16 + quad*4 + r, q = l15 ----
    f32x4 st[4];
#pragma unroll
    for (int s4 = 0; s4 < 4; ++s4) {
      const u16* kr = &Ks[buf][(s4 * 16 + l15) * 64];
      const bf16x8 kf0 = *(const bf16x8*)(kr + ((quad ^ swz) << 3));
      const bf16x8 kf1 = *(const bf16x8*)(kr + (((4 | quad) ^ swz) << 3));
      f32x4 a = {};
      a = __builtin_amdgcn_mfma_f32_16x16x32_bf16(kf0, qf0, a, 0, 0, 0);
      a = __builtin_amdgcn_mfma_f32_16x16x32_bf16(kf1, qf1, a, 0, 0, 0);
      st[s4] = a;
    }

    // ---- softmax (scores already in log2 domain via pre-scaled Q) ----
    float s[16];
#pragma unroll
    for (int s4 = 0; s4 < 4; ++s4)
#pragma unroll
      for (int r = 0; r < 4; ++r) s[s4 * 4 + r] = st[s4][r];
    if (t == ntiles - 1) {  // diagonal tile: the only one needing the mask
#pragma unroll
      for (int s4 = 0; s4 < 4; ++s4)
#pragma unroll
        for (int r = 0; r < 4; ++r) {
          const int kv = n0 + s4 * 16 + quad * 4 + r;
          if (kv > m) s[s4 * 4 + r] = -INFINITY;
        }
    }
    float t8[8], t4[4];
#pragma unroll
    for (int i = 0; i < 8; ++i) t8[i] = fmaxf(s[i], s[i + 8]);
#pragma unroll
    for (int i = 0; i < 4; ++i) t4[i] = fmaxf(t8[i], t8[i + 4]);
    float mx = fmaxf(fmaxf(t4[0], t4[1]), fmaxf(t4[2], t4[3]));
    mx = fmaxf(mx, __shfl_xor(mx, 16));
    mx = fmaxf(mx, __shfl_xor(mx, 32));

    float mbase;
    if (__all(mx <= m_run + 8.0f)) {
      mbase = m_run;                     // defer: P bounded by 2^8, bf16-safe
    } else {
      mbase = fmaxf(m_run, mx);
      const float alpha = exp2f(m_run - mbase);  // 0 on first tile
      l_lane *= alpha;
#pragma unroll
      for (int dt = 0; dt < 4; ++dt) o[dt] *= alpha;
      m_run = mbase;
    }

    float p[16];
#pragma unroll
    for (int i = 0; i < 16; ++i) p[i] = exp2f(s[i] - mbase);
    float u8[8], u4[4];
#pragma unroll
    for (int i = 0; i < 8; ++i) u8[i] = p[i] + p[i + 8];
#pragma unroll
    for (int i = 0; i < 4; ++i) u4[i] = u8[i] + u8[i + 4];
    l_lane += (u4[0] + u4[1]) + (u4[2] + u4[3]);  // lane-local; reduce at end

    // ---- P -> LDS, stride 64 + chunk XOR swizzle; cvt_pk packing ----
#pragma unroll
    for (int s4 = 0; s4 < 4; ++s4) {
      u32 c0, c1;
      asm("v_cvt_pk_bf16_f32 %0, %1, %2"
          : "=v"(c0) : "v"(p[s4 * 4 + 0]), "v"(p[s4 * 4 + 1]));
      asm("v_cvt_pk_bf16_f32 %0, %1, %2"
          : "=v"(c1) : "v"(p[s4 * 4 + 2]), "v"(p[s4 * 4 + 3]));
      const int wchunk = ((s4 * 2 + (quad >> 1)) ^ swz) << 3;
      u32x2 w = { c0, c1 };
      *(u32x2*)&plds[l15 * 64 + wchunk + ((quad & 1) << 2)] = w;
    }
    asm volatile("s_waitcnt lgkmcnt(0)" ::: "memory");

    // ---- PV: o[dt] row = d = dt*16 + quad*4 + r, col = q = l15 ----
#pragma unroll
    for (int ks = 0; ks < 2; ++ks) {
      const bf16x8 pf =
          *(const bf16x8*)&plds[l15 * 64 + (((ks * 4 + quad) ^ swz) << 3)];
#pragma unroll
      for (int dt = 0; dt < 4; ++dt) {
        const u16* vr = &Vs[buf][(dt * 16 + l15) * 64];
        const bf16x8 vf =
            *(const bf16x8*)(vr + ((((ks << 2) | quad) ^ swz) << 3));
        o[dt] = __builtin_amdgcn_mfma_f32_16x16x32_bf16(vf, pf, o[dt], 0, 0, 0);
      }
    }

    __syncthreads();  // drains vmcnt(0): next tile staged; buf safe to reuse
    buf ^= 1;
  }

  float l = l_lane;
  l += __shfl_xor(l, 16);
  l += __shfl_xor(l, 32);
  const float inv = 1.0f / l;
  u16* crow = ctx + ((size_t)(b * 2048 + m) * 1024 + h * 64);
#pragma unroll
  for (int dt = 0; dt < 4; ++dt) {
    bf16x4 ov = { (short)f2b(o[dt][0] * inv), (short)f2b(o[dt][1] * inv),
                  (short)f2b(o[dt][2] * inv), (short)f2b(o[dt][3] * inv) };
    *(bf16x4*)&crow[dt * 16 + quad * 4] = ov;
  }
}

// ---------------------------------------------------------------------------
extern "C" void kernel_launch(void* const* d_in, const int* in_sizes, int n_in,
                              void* d_out, int out_size, void* d_ws,
                              size_t ws_size, hipStream_t stream) {
  // Interface (R9-verified): inputs fp32 in dict order, output fp32.
  const float* x  = (const float*)d_in[0];
  const float* wq = (const float*)d_in[1];
  const float* wk = (const float*)d_in[2];
  const float* wv = (const float*)d_in[3];
  const float* wo = (const float*)d_in[4];
  const float* bo = (const float*)d_in[5];
  float* out = (float*)d_out;

  // ws (bf16 elems): qb [0,4M) (aliased as ctx), kb [4M,8M),
  // vt [8M,12M) transposed V. 24 MiB.
  u16* qb = (u16*)d_ws;
  u16* kb = qb + 4194304u;
  u16* vt = kb + 4194304u;
  u16* ctx = qb;

  // d_out doubles as pre-converted-operand scratch until gemm_out runs:
  // xb [0, 8MiB) = x in bf16; wb [8, 14MiB) = Wq|Wk|Wv in bf16.
  u16* xb = (u16*)d_out;
  u16* wb = xb + 4194304u;
  // Wo bf16 goes into kb, which is dead after flash_kernel.
  u16* wob = kb;

  convert_qw_kernel<<<3584, 256, 0, stream>>>(x, wq, wk, wv, xb, wb);
  gemm_qkv_kernel<<<dim3(32, 24), 256, 0, stream>>>(xb, wb, qb, kb, vt);
  flash_kernel<<<1024, 256, 0, stream>>>(qb, kb, vt, ctx);
  convert_wo_kernel<<<512, 256, 0, stream>>>(wo, wob);
  gemm_out_kernel<<<dim3(32, 8), 256, 0, stream>>>(ctx, wob, bo, out);
}